// Round 2
// baseline (494.184 us; speedup 1.0000x reference)
//
#include <hip/hip_runtime.h>

// Cosine similarity per row: q,d are [N, 256] fp32; out is [N] fp32.
//
// Structure (unchanged from R1): 16 lanes per row, 4 rows per wave, 4 fx4
// chunks per lane. Per-lane register accumulation of qq/dd/qd, then a
// 4-step xor butterfly (offsets 8,4,2,1 stay inside the 16-lane group).
//
// R2 change: loads are REGULAR (cached) instead of nontemporal.
// Rationale: the measured 6.29 TB/s streaming ceiling (m13) and the
// ~6.7 TB/s harness fills both go through the cache hierarchy; the nt
// (no-allocate) read path is unverified on gfx950 and is the one
// remaining untested variable after R1's reduction restructure proved
// neutral. Cache pollution is a non-issue: inputs are read exactly once
// and the harness's 1 GiB poison fill evicts L2/L3 every iteration
// anyway. Store stays nontemporal (write-once, tiny).
// Memory floor: 512 MiB in, 1 MiB out -> ~85 us at 6.3 TB/s.
typedef float fx4 __attribute__((ext_vector_type(4)));

constexpr int ROWS_PER_WAVE = 4;   // 64 lanes / 16 lanes-per-row
constexpr int WAVES_PER_BLOCK = 4; // 256 threads

__global__ __launch_bounds__(256) void cosine_rows_kernel(
    const fx4* __restrict__ q4,   // [N, 64] fx4 view of [N,256] f32
    const fx4* __restrict__ d4,
    float* __restrict__ out,      // [N] f32
    int n_rows)
{
    const int wave = (blockIdx.x * blockDim.x + threadIdx.x) >> 6;
    const int lane = threadIdx.x & 63;
    const int g    = lane >> 4;    // which of the wave's 4 rows
    const int c    = lane & 15;    // chunk lane within the row
    const int row  = wave * ROWS_PER_WAVE + g;
    if (row >= n_rows) return;

    // Row has 64 fx4 chunks; this lane takes chunks c, c+16, c+32, c+48.
    // Per load instruction a 16-lane group covers one contiguous 256 B
    // segment of its row; 8 independent loads issued back-to-back.
    const size_t base = (size_t)row * 64 + c;

    fx4 qv[4], dv[4];
    #pragma unroll
    for (int k = 0; k < 4; ++k)
        qv[k] = q4[base + 16 * k];
    #pragma unroll
    for (int k = 0; k < 4; ++k)
        dv[k] = d4[base + 16 * k];

    float qq = 0.0f, dd = 0.0f, qd = 0.0f;
    #pragma unroll
    for (int k = 0; k < 4; ++k) {
        qq += qv[k].x * qv[k].x + qv[k].y * qv[k].y +
              qv[k].z * qv[k].z + qv[k].w * qv[k].w;
        dd += dv[k].x * dv[k].x + dv[k].y * dv[k].y +
              dv[k].z * dv[k].z + dv[k].w * dv[k].w;
        qd += qv[k].x * dv[k].x + qv[k].y * dv[k].y +
              qv[k].z * dv[k].z + qv[k].w * dv[k].w;
    }

    // 4-step butterfly across the 16-lane group (xor masks < 16 never
    // cross the group boundary).
    #pragma unroll
    for (int off = 8; off > 0; off >>= 1) {
        qq += __shfl_xor(qq, off, 64);
        dd += __shfl_xor(dd, off, 64);
        qd += __shfl_xor(qd, off, 64);
    }

    if (c == 0) {
        // Lanes 0,16,32,48 write rows row..row+3 of this wave's block:
        // four 4 B stores, same 16 B segment.
        __builtin_nontemporal_store(qd * rsqrtf(qq * dd), &out[row]);
    }
}

extern "C" void kernel_launch(void* const* d_in, const int* in_sizes, int n_in,
                              void* d_out, int out_size, void* d_ws, size_t ws_size,
                              hipStream_t stream) {
    const fx4* q4 = (const fx4*)d_in[0];
    const fx4* d4 = (const fx4*)d_in[1];
    float* out = (float*)d_out;

    const int D = 256;
    const int n_rows = in_sizes[0] / D;   // 262144

    // 4 waves/block x 4 rows/wave = 16 rows per block.
    const int rows_per_block = WAVES_PER_BLOCK * ROWS_PER_WAVE;
    const int grid = (n_rows + rows_per_block - 1) / rows_per_block;

    cosine_rows_kernel<<<grid, 256, 0, stream>>>(q4, d4, out, n_rows);
}

// Round 3
// 471.235 us; speedup vs baseline: 1.0487x; 1.0487x over previous
//
#include <hip/hip_runtime.h>

// Cosine similarity per row: q,d are [N, 256] fp32; out is [N] fp32.
//
// Structure: 16 lanes per row, 4 rows per wave-group, persistent
// grid-stride. R3 changes vs R1:
//   * nt loads RESTORED (R2 proved cached loads cost +28 us total).
//   * persistent kernel: 2048 blocks grid-stride instead of 16384
//     one-shot blocks. Eliminates wave churn -- each wave previously
//     moved only 8 KiB over a ~1200-cycle lifetime (~6.8 B/cyc vs the
//     10.25 B/cyc/CU needed for 6.3 TB/s), with an idle exit/relaunch
//     tail. Now each wave streams ~32 row-groups back-to-back.
//   * 2 row-groups per loop iteration, all 16 loads issued before any
//     consumption: group 1's loads remain in flight (vmcnt(8)) while
//     group 0 reduces.
// Memory floor: 512 MiB in, 1 MiB out -> ~82 us at 6.3 TB/s.
typedef float fx4 __attribute__((ext_vector_type(4)));

constexpr int ROWS_PER_GROUP = 4;   // 64 lanes / 16 lanes-per-row
constexpr int GROUPS_PER_ITER = 2;  // unrolled per-wave per iteration
constexpr int BLOCKS = 2048;        // ~8 blocks/CU worth of waves, grid-stride

__global__ __launch_bounds__(256) void cosine_rows_kernel(
    const fx4* __restrict__ q4,   // [N, 64] fx4 view of [N,256] f32
    const fx4* __restrict__ d4,
    float* __restrict__ out,      // [N] f32
    int n_rows)
{
    const int nwaves = (gridDim.x * blockDim.x) >> 6;
    const int wave   = (blockIdx.x * blockDim.x + threadIdx.x) >> 6;
    const int lane   = threadIdx.x & 63;
    const int g      = lane >> 4;    // which of the group's 4 rows
    const int c      = lane & 15;    // chunk lane within the row

    const int total_groups = n_rows >> 2;  // groups of 4 rows

    for (int grp = wave * GROUPS_PER_ITER; grp < total_groups;
         grp += nwaves * GROUPS_PER_ITER) {

        // Issue ALL loads for both groups before any consumption.
        fx4 qv[GROUPS_PER_ITER][4], dv[GROUPS_PER_ITER][4];
        #pragma unroll
        for (int u = 0; u < GROUPS_PER_ITER; ++u) {
            if (grp + u < total_groups) {
                const int row = (grp + u) * ROWS_PER_GROUP + g;
                const size_t base = (size_t)row * 64 + c;
                #pragma unroll
                for (int k = 0; k < 4; ++k)
                    qv[u][k] = __builtin_nontemporal_load(&q4[base + 16 * k]);
                #pragma unroll
                for (int k = 0; k < 4; ++k)
                    dv[u][k] = __builtin_nontemporal_load(&d4[base + 16 * k]);
            }
        }

        #pragma unroll
        for (int u = 0; u < GROUPS_PER_ITER; ++u) {
            if (grp + u < total_groups) {
                float qq = 0.0f, dd = 0.0f, qd = 0.0f;
                #pragma unroll
                for (int k = 0; k < 4; ++k) {
                    qq += qv[u][k].x * qv[u][k].x + qv[u][k].y * qv[u][k].y +
                          qv[u][k].z * qv[u][k].z + qv[u][k].w * qv[u][k].w;
                    dd += dv[u][k].x * dv[u][k].x + dv[u][k].y * dv[u][k].y +
                          dv[u][k].z * dv[u][k].z + dv[u][k].w * dv[u][k].w;
                    qd += qv[u][k].x * dv[u][k].x + qv[u][k].y * dv[u][k].y +
                          qv[u][k].z * dv[u][k].z + qv[u][k].w * dv[u][k].w;
                }

                // 4-step butterfly within the 16-lane group.
                #pragma unroll
                for (int off = 8; off > 0; off >>= 1) {
                    qq += __shfl_xor(qq, off, 64);
                    dd += __shfl_xor(dd, off, 64);
                    qd += __shfl_xor(qd, off, 64);
                }

                if (c == 0) {
                    const int row = (grp + u) * ROWS_PER_GROUP + g;
                    __builtin_nontemporal_store(qd * rsqrtf(qq * dd), &out[row]);
                }
            }
        }
    }
}

extern "C" void kernel_launch(void* const* d_in, const int* in_sizes, int n_in,
                              void* d_out, int out_size, void* d_ws, size_t ws_size,
                              hipStream_t stream) {
    const fx4* q4 = (const fx4*)d_in[0];
    const fx4* d4 = (const fx4*)d_in[1];
    float* out = (float*)d_out;

    const int D = 256;
    const int n_rows = in_sizes[0] / D;   // 262144

    const int total_groups = n_rows / ROWS_PER_GROUP;
    const int waves_needed = (total_groups + GROUPS_PER_ITER - 1) / GROUPS_PER_ITER;
    const int blocks_needed = (waves_needed + 3) / 4;   // 4 waves/block
    const int grid = min(BLOCKS, blocks_needed);

    cosine_rows_kernel<<<grid, 256, 0, stream>>>(q4, d4, out, n_rows);
}